// Round 8
// baseline (692.370 us; speedup 1.0000x reference)
//
#include <hip/hip_runtime.h>

// Problem constants
#define B_SZ   64
#define S_LEN  200
#define H_DIM  1024
#define NHEAD  16
#define HDIM   64
#define FF_DIM 4096
#define NROWS  (B_SZ * S_LEN)   // 12800

typedef __bf16 bf16x8 __attribute__((ext_vector_type(8)));
typedef float  f32x4  __attribute__((ext_vector_type(4)));

#define GLOBAL_AS __attribute__((address_space(1)))
#define LDS_AS    __attribute__((address_space(3)))

__device__ __forceinline__ void g2lds16(const void* g, void* l) {
  __builtin_amdgcn_global_load_lds((const GLOBAL_AS void*)g, (LDS_AS void*)l, 16, 0, 0);
}

__device__ __forceinline__ float b2f(ushort u) {
  return __uint_as_float(((unsigned int)u) << 16);
}
__device__ __forceinline__ ushort f2b(float f) {
  unsigned int u = __float_as_uint(f);
  u += 0x7fffu + ((u >> 16) & 1u);   // RNE
  return (ushort)(u >> 16);
}
__device__ __forceinline__ bf16x8 ld_g16(const ushort* p) {   // 16B global load
  union { uint4 u; bf16x8 v; } r; r.u = *(const uint4*)p; return r.v;
}
__device__ __forceinline__ bf16x8 ld_lds8x2(const ushort* p) { // 2x ds_read_b64
  union { uint2 u[2]; bf16x8 v; } r;
  r.u[0] = *(const uint2*)p;
  r.u[1] = *(const uint2*)(p + 4);
  return r.v;
}

// ---------------------------------------------------------------------------
// Fast exact-GELU: erf via Abramowitz-Stegun 7.1.26 (|err|<=1.5e-7).
// ---------------------------------------------------------------------------
__device__ __forceinline__ float fast_gelu(float v) {
  float xe = v * 0.70710678118f;
  float ax = fabsf(xe);
  float t  = __builtin_amdgcn_rcpf(fmaf(0.3275911f, ax, 1.0f));
  float y  = fmaf(t, 1.061405429f, -1.453152027f);
  y = fmaf(t, y, 1.421413741f);
  y = fmaf(t, y, -0.284496736f);
  y = fmaf(t, y, 0.254829592f);
  y = y * t;
  float e  = __expf(-ax * ax);
  float r  = fmaf(-y, e, 1.0f);            // erf(|xe|)
  r = copysignf(r, xe);
  return 0.5f * v * (1.0f + r);
}

// ---------------------------------------------------------------------------
// LN1 row body (shared by fused-prep and standalone LN2 kernel).
// ---------------------------------------------------------------------------
template <int HAS_TIME>
__device__ __forceinline__ void ln_row(
    int r, int lane,
    const float* __restrict__ x, const float* __restrict__ g, const float* __restrict__ be,
    const float* __restrict__ tv, const float* __restrict__ wt, const float* __restrict__ bt,
    ushort* __restrict__ out) {
  const float4* xr = (const float4*)(x + (size_t)r * H_DIM);
  float4 xv[4];
  float s = 0.f, s2 = 0.f;
#pragma unroll
  for (int k = 0; k < 4; ++k) {
    xv[k] = xr[lane + 64 * k];
    s  += xv[k].x + xv[k].y + xv[k].z + xv[k].w;
    s2 += xv[k].x * xv[k].x + xv[k].y * xv[k].y + xv[k].z * xv[k].z + xv[k].w * xv[k].w;
  }
#pragma unroll
  for (int off = 32; off; off >>= 1) {
    s  += __shfl_xor(s, off);
    s2 += __shfl_xor(s2, off);
  }
  float m    = s * (1.0f / H_DIM);
  float var  = s2 * (1.0f / H_DIM) - m * m;
  float rstd = rsqrtf(var + 1e-5f);
  float tval = HAS_TIME ? tv[r] : 0.0f;
  ushort4* orow = (ushort4*)(out + (size_t)r * H_DIM);
#pragma unroll
  for (int k = 0; k < 4; ++k) {
    float4 gv = ((const float4*)g)[lane + 64 * k];
    float4 bv = ((const float4*)be)[lane + 64 * k];
    float v0 = (xv[k].x - m) * rstd * gv.x + bv.x;
    float v1 = (xv[k].y - m) * rstd * gv.y + bv.y;
    float v2 = (xv[k].z - m) * rstd * gv.z + bv.z;
    float v3 = (xv[k].w - m) * rstd * gv.w + bv.w;
    if (HAS_TIME) {
      float4 wv = ((const float4*)wt)[lane + 64 * k];
      float4 btv = ((const float4*)bt)[lane + 64 * k];
      v0 += tval * wv.x + btv.x;
      v1 += tval * wv.y + btv.y;
      v2 += tval * wv.z + btv.z;
      v3 += tval * wv.w + btv.w;
    }
    ushort4 o;
    o.x = f2b(v0); o.y = f2b(v1); o.z = f2b(v2); o.w = f2b(v3);
    orow[lane + 64 * k] = o;
  }
}

// ---------------------------------------------------------------------------
// Mega prep kernel: 6 weight transposes + bias concat + pos slice + LN1.
// Blocks 0..12287: transpose tiles.  12288: extras.  12289..15488: LN1 rows.
// ---------------------------------------------------------------------------
__global__ __launch_bounds__(256) void prep_kernel(
    const float* __restrict__ wq, const float* __restrict__ wk,
    const float* __restrict__ wv, const float* __restrict__ wo,
    const float* __restrict__ w1, const float* __restrict__ w2,
    const float* __restrict__ bq, const float* __restrict__ bk,
    const float* __restrict__ bv_, const float* __restrict__ pos,
    ushort* __restrict__ wqkv_t, ushort* __restrict__ wo_t,
    ushort* __restrict__ w1_t, ushort* __restrict__ w2_t,
    float* __restrict__ bqkv, ushort* __restrict__ pos_bf,
    const float* __restrict__ x, const float* __restrict__ g1,
    const float* __restrict__ be1, const float* __restrict__ tv,
    const float* __restrict__ wt, const float* __restrict__ bt,
    ushort* __restrict__ hbf) {
  int id = blockIdx.x;
  if (id < 12288) {
    const float* src; ushort* dst; int K, N, tile;
    if (id < 4096) {
      K = 1024; N = 1024; tile = id & 1023;
      int m = id >> 10;  // 0:wq 1:wk 2:wv 3:wo
      src = (m == 0) ? wq : (m == 1) ? wk : (m == 2) ? wv : wo;
      dst = (m == 3) ? wo_t : wqkv_t + (size_t)m * 1024 * 1024;
    } else if (id < 8192) {
      K = 1024; N = 4096; tile = id - 4096; src = w1; dst = w1_t;
    } else {
      K = 4096; N = 1024; tile = id - 8192; src = w2; dst = w2_t;
    }
    int nx = N >> 5;
    int nb = (tile % nx) * 32, kb = (tile / nx) * 32;
    __shared__ float t32[32][33];
    int tx = threadIdx.x & 31, ty = threadIdx.x >> 5;   // 32 x 8
#pragma unroll
    for (int i = 0; i < 4; ++i)
      t32[ty + i * 8][tx] = src[(size_t)(kb + ty + i * 8) * N + nb + tx];
    __syncthreads();
#pragma unroll
    for (int i = 0; i < 4; ++i)
      dst[(size_t)(nb + ty + i * 8) * K + kb + tx] = f2b(t32[tx][ty + i * 8]);
  } else if (id == 12288) {
    int t = threadIdx.x;
    for (int i = t; i < 1024; i += 256) {
      bqkv[i] = bq[i]; bqkv[1024 + i] = bk[i]; bqkv[2048 + i] = bv_[i];
    }
    for (int i = t; i < 12800; i += 256)
      pos_bf[i] = f2b(pos[(size_t)199 * 64 + i]);
  } else {
    int wave = threadIdx.x >> 6, lane = threadIdx.x & 63;
    int r = (id - 12289) * 4 + wave;
    ln_row<1>(r, lane, x, g1, be1, tv, wt, bt, hbf);
  }
}

// ---------------------------------------------------------------------------
// Standalone LN (LN2): 4 rows/block, one wave per row.
// ---------------------------------------------------------------------------
__global__ __launch_bounds__(256) void ln_kernel(
    const float* __restrict__ x, const float* __restrict__ g, const float* __restrict__ be,
    ushort* __restrict__ out) {
  int wave = threadIdx.x >> 6, lane = threadIdx.x & 63;
  int r = blockIdx.x * 4 + wave;
  ln_row<0>(r, lane, x, g, be, nullptr, nullptr, nullptr, out);
}

// ---------------------------------------------------------------------------
// 128x128 GEMM (chunked-FF2 fallback only).  Row-major XCD decode.
// ---------------------------------------------------------------------------
template <int EPI>
__global__ __launch_bounds__(256) void gemm_bt(
    const ushort* __restrict__ A, const ushort* __restrict__ Bt,
    const float* __restrict__ bias, void* __restrict__ Cv,
    const float* __restrict__ resid, int M, int N, int K) {
  __shared__ __align__(16) ushort As[2 * 128 * 32];   // [kh][row][32]
  __shared__ __align__(16) ushort Bs[2 * 128 * 32];
  int t = threadIdx.x;
  int lane = t & 63, wave = t >> 6;
  int wm = wave >> 1, wn = wave & 1;
  int r15 = lane & 15, quad = lane >> 4;
  int nwg = gridDim.x * gridDim.y;
  int bid = blockIdx.y * gridDim.x + blockIdx.x;
  int swz = (bid & 7) * (nwg >> 3) + (bid >> 3);
  int bx = swz % gridDim.x, by = swz / gridDim.x;
  size_t row0 = (size_t)by * 128;
  size_t col0 = (size_t)bx * 128;

  int srow = (lane >> 2), scol = (lane & 3) * 8;
  const ushort* ga0 = A  + (row0 + wave * 32 +      srow) * K + scol;
  const ushort* ga1 = A  + (row0 + wave * 32 + 16 + srow) * K + scol;
  const ushort* gb0 = Bt + (col0 + wave * 32 +      srow) * K + scol;
  const ushort* gb1 = Bt + (col0 + wave * 32 + 16 + srow) * K + scol;
  ushort* la0 = As + (wave * 32) * 32;
  ushort* la1 = As + (wave * 32 + 16) * 32;
  ushort* lb0 = Bs + (wave * 32) * 32;
  ushort* lb1 = Bs + (wave * 32 + 16) * 32;

  f32x4 acc[4][4] = {};

  for (int k0 = 0; k0 < K; k0 += 64) {
#pragma unroll
    for (int kh = 0; kh < 2; ++kh) {
      int go = k0 + kh * 32, lo = kh * 4096;
      g2lds16(ga0 + go, la0 + lo);
      g2lds16(ga1 + go, la1 + lo);
      g2lds16(gb0 + go, lb0 + lo);
      g2lds16(gb1 + go, lb1 + lo);
    }
    __syncthreads();
#pragma unroll
    for (int kh = 0; kh < 2; ++kh) {
      bf16x8 af[4], bfr[4];
#pragma unroll
      for (int i = 0; i < 4; ++i)
        af[i] = *(const bf16x8*)&As[kh * 4096 + (wm * 64 + i * 16 + r15) * 32 + quad * 8];
#pragma unroll
      for (int j = 0; j < 4; ++j)
        bfr[j] = *(const bf16x8*)&Bs[kh * 4096 + (wn * 64 + j * 16 + r15) * 32 + quad * 8];
#pragma unroll
      for (int i = 0; i < 4; ++i)
#pragma unroll
        for (int j = 0; j < 4; ++j)
          acc[i][j] = __builtin_amdgcn_mfma_f32_16x16x32_bf16(af[i], bfr[j], acc[i][j], 0, 0, 0);
    }
    __syncthreads();
  }

  int mbase = (int)row0 + wm * 64;
  int nbase = (int)col0 + wn * 64;
  float bb[4];
#pragma unroll
  for (int j = 0; j < 4; ++j) bb[j] = bias[nbase + j * 16 + r15];
#pragma unroll
  for (int i = 0; i < 4; ++i) {
#pragma unroll
    for (int ii = 0; ii < 4; ++ii) {
      int row = mbase + i * 16 + quad * 4 + ii;
      size_t rb = (size_t)row * N + nbase + r15;
#pragma unroll
      for (int j = 0; j < 4; ++j) {   // j innermost: 4 stores share a 128B line
        size_t idx = rb + j * 16;
        float v = acc[i][j][ii] + bb[j];
        if constexpr (EPI == 0) {
          ((ushort*)Cv)[idx] = f2b(v);
        } else if constexpr (EPI == 1) {
          ((ushort*)Cv)[idx] = f2b(fast_gelu(v));
        } else {
          ((float*)Cv)[idx] = v + resid[idx];
        }
      }
    }
  }
}

// ---------------------------------------------------------------------------
// 256x256 8-phase GEMM (round-4 schedule, best measured).
// Row-major XCD decode; write-combined epilogue.
// ---------------------------------------------------------------------------
template <int IB>
__device__ __forceinline__ void mfma_blk(f32x4 (&acc)[8][4],
                                         const bf16x8 (&af)[4], const bf16x8 (&bfr)[4]) {
#pragma unroll
  for (int i = 0; i < 4; ++i)
#pragma unroll
    for (int j = 0; j < 4; ++j)
      acc[IB + i][j] =
          __builtin_amdgcn_mfma_f32_16x16x32_bf16(af[i], bfr[j], acc[IB + i][j], 0, 0, 0);
}

__device__ __forceinline__ bf16x8 rdfrag(const ushort* plane, int r, int quad) {
  // logical (row r, 16B-slot quad) -> physical slot quad ^ ((r>>1)&3)
  return *(const bf16x8*)(plane + r * 32 + ((quad ^ ((r >> 1) & 3)) << 3));
}

__device__ __forceinline__ void read_q0(bf16x8 (&af)[4], bf16x8 (&bfr)[4],
                                        const ushort* pA, const ushort* pB,
                                        int wn1, int r15, int quad) {
#pragma unroll
  for (int j = 0; j < 4; ++j) bfr[j] = rdfrag(pB, wn1 * 64 + j * 16 + r15, quad);
#pragma unroll
  for (int i = 0; i < 4; ++i) af[i] = rdfrag(pA, i * 16 + r15, quad);
}
__device__ __forceinline__ void read_q1(bf16x8 (&af)[4], const ushort* pA,
                                        int r15, int quad) {
#pragma unroll
  for (int i = 0; i < 4; ++i) af[i] = rdfrag(pA, 64 + i * 16 + r15, quad);
}

#define VMW8() asm volatile("s_waitcnt vmcnt(8)" ::: "memory")
#define VMW4() asm volatile("s_waitcnt vmcnt(4)" ::: "memory")
#define VMW0() asm volatile("s_waitcnt vmcnt(0)" ::: "memory")
#define BARX() __builtin_amdgcn_s_barrier()
#define PRIO1() __builtin_amdgcn_s_setprio(1)
#define PRIO0() __builtin_amdgcn_s_setprio(0)

template <int EPI>
__global__ __launch_bounds__(512) void gemm256(
    const ushort* __restrict__ A, const ushort* __restrict__ Bt,
    const float* __restrict__ bias, void* __restrict__ Cv,
    const float* __restrict__ resid, int M, int N, int K) {
  __shared__ __align__(16) ushort lds[2][2][2][2][4096];  // [buf][A/B][half][kh][128*32]
  const int t = threadIdx.x;
  const int lane = t & 63, wave = t >> 6;
  const int wm = wave >> 2;            // A half this wave consumes
  const int wn = wave & 3;
  const int wn1 = wn & 1;
  const int bh = wn >> 1;              // B half this wave consumes
  const int r15 = lane & 15, quad = lane >> 4;
  // XCD swizzle (T1), row-major decode: consecutive swz share by (A-panel)
  int nwg = gridDim.x * gridDim.y;
  int bid = blockIdx.y * gridDim.x + blockIdx.x;
  int swz = (bid & 7) * (nwg >> 3) + (bid >> 3);
  int bx = swz % gridDim.x, by = swz / gridDim.x;
  const size_t row0 = (size_t)by * 256;
  const size_t col0 = (size_t)bx * 256;

  const int gwA = wave & 3;
  const int gwB = ((wave >> 1) & 2) | (wave & 1);

  const ushort *gA0, *gA1, *gB0, *gB1;
  {
    int p0 = gwA * 128 + lane;
    int p1 = p0 + 64;
    int ra0 = p0 >> 2, sa0 = (p0 & 3) ^ ((p0 >> 3) & 3);
    int ra1 = p1 >> 2, sa1 = (p1 & 3) ^ ((p1 >> 3) & 3);
    gA0 = A + (row0 + wm * 128 + ra0) * K + sa0 * 8;
    gA1 = A + (row0 + wm * 128 + ra1) * K + sa1 * 8;
    int q0 = gwB * 128 + lane;
    int q1 = q0 + 64;
    int rb0 = q0 >> 2, sb0 = (q0 & 3) ^ ((q0 >> 3) & 3);
    int rb1 = q1 >> 2, sb1 = (q1 & 3) ^ ((q1 >> 3) & 3);
    gB0 = Bt + (col0 + bh * 128 + rb0) * K + sb0 * 8;
    gB1 = Bt + (col0 + bh * 128 + rb1) * K + sb1 * 8;
  }
  const int ldsA0 = gwA * 1024, ldsA1 = gwA * 1024 + 512;   // ushort offsets
  const int ldsB0 = gwB * 1024, ldsB1 = gwB * 1024 + 512;

#define STAGE_A(nb_, skh_, kof_)                                        \
  do {                                                                  \
    g2lds16(gA0 + (kof_) + (skh_) * 32, &lds[nb_][0][wm][skh_][ldsA0]); \
    g2lds16(gA1 + (kof_) + (skh_) * 32, &lds[nb_][0][wm][skh_][ldsA1]); \
  } while (0)
#define STAGE_B(nb_, skh_, kof_)                                        \
  do {                                                                  \
    g2lds16(gB0 + (kof_) + (skh_) * 32, &lds[nb_][1][bh][skh_][ldsB0]); \
    g2lds16(gB1 + (kof_) + (skh_) * 32, &lds[nb_][1][bh][skh_][ldsB1]); \
  } while (0)
#define PAP(b_, k_) (&lds[b_][0][wm][k_][0])
#define PBP(b_, k_) (&lds[b_][1][bh][k_][0])

  f32x4 acc[8][4] = {};

  // prologue: tile0 full + tile1 kh0 (6 stage ops = 12 loads/thread)
  STAGE_A(0, 0, 0);
  STAGE_B(0, 0, 0);
  STAGE_A(0, 1, 0);
  STAGE_B(0, 1, 0);
  STAGE_A(1, 0, 64);
  STAGE_B(1, 0, 64);
  VMW8();                       // tile0 kh0 (A,B) resident; 8 loads in flight
  BARX();

#define ITER_BODY(LAST_, ka_)                                                  \
  {                                                                            \
    bf16x8 af[4], bfr[4];                                                      \
    /* P0: buf0 kh0 Q0 */                                                      \
    read_q0(af, bfr, PAP(0, 0), PBP(0, 0), wn1, r15, quad);                    \
    STAGE_A(1, 1, (ka_) + 64);                                                 \
    BARX(); PRIO1(); mfma_blk<0>(acc, af, bfr); PRIO0(); BARX();               \
    /* P1: buf0 kh0 Q1 */                                                      \
    read_q1(af, PAP(0, 0), r15, quad);                                         \
    STAGE_B(1, 1, (ka_) + 64);                                                 \
    BARX(); PRIO1(); mfma_blk<4>(acc, af, bfr); PRIO0();                       \
    VMW8(); BARX();                                                            \
    /* P2: buf0 kh1 Q0 */                                                      \
    read_q0(af, bfr, PAP(0, 1), PBP(0, 1), wn1, r15, quad);                    \
    if (!(LAST_)) STAGE_A(0, 0, (ka_) + 128);                                  \
    BARX(); PRIO1(); mfma_blk<0>(acc, af, bfr); PRIO0(); BARX();               \
    /* P3: buf0 kh1 Q1 */                                                      \
    read_q1(af, PAP(0, 1), r15, quad);                                         \
    if (!(LAST_)) STAGE_B(0, 0, (ka_) + 128);                                  \
    BARX(); PRIO1(); mfma_blk<4>(acc, af, bfr); PRIO0();                       \
    if (LAST_) { VMW4(); } else { VMW8(); }                                    \
    BARX();                                                                    \
    /* P4: buf1 kh0 Q0 */                                                      \
    read_q0(af, bfr, PAP(1, 0), PBP(1, 0), wn1, r15, quad);                    \
    if (!(LAST_)) STAGE_A(0, 1, (ka_) + 128);                                  \
    BARX(); PRIO1(); mfma_blk<0>(acc, af, bfr); PRIO0(); BARX();               \
    /* P5: buf1 kh0 Q1 */                                                      \
    read_q1(af, PAP(1, 0), r15, quad);                                         \
    if (!(LAST_)) STAGE_B(0, 1, (ka_) + 128);                                  \
    BARX(); PRIO1(); mfma_blk<4>(acc, af, bfr); PRIO0();                       \
    if (LAST_) { VMW0(); } else { VMW8(); }                                    \
    BARX();                                                                    \
    /* P6: buf1 kh1 Q0 */                                                      \
    read_q0(af, bfr, PAP(1, 1), PBP(1, 1), wn1, r15, quad);                    \
    if (!(LAST_)) STAGE_A(1, 0, (ka_) + 192);                                  \
    BARX(); PRIO1(); mfma_blk<0>(acc, af, bfr); PRIO0(); BARX();               \
    /* P7: buf1 kh1 Q1 */                                                      \
    read_q1(af, PAP(1, 1), r15, quad);                                         \
    if (!(LAST_)) STAGE_B(1, 0, (ka_) + 192);                                  \
    BARX(); PRIO1(); mfma_blk<4>(acc, af, bfr); PRIO0();                       \
    if (!(LAST_)) { VMW8(); }                                                  \
    BARX();                                                                    \
  }

  const int NI = K >> 7;   // two 64-wide K-tiles per iteration
  for (int it = 0; it < NI - 1; ++it) {
    ITER_BODY(0, it << 7);
  }
  ITER_BODY(1, (NI - 1) << 7);
#undef ITER_BODY

  // epilogue (write-combined: j innermost so 4 stores share a 128B line)
  int mbase = (int)row0 + wm * 128;
  int nbase = (int)col0 + wn * 64;
  float bb[4];
#pragma unroll
  for (int j = 0; j < 4; ++j) bb[j] = bias[nbase + j * 16 + r15];
#pragma unroll
  for (int i = 0; i < 8; ++i) {
#pragma unroll
    for (int ii = 0; ii < 4; ++ii) {
      int row = mbase + i * 16 + quad * 4 + ii;
      size_t rb = (size_t)row * N + nbase + r15;
#pragma unroll
      for (int j = 0; j < 4; ++j) {
        size_t idx = rb + j * 16;
        float v = acc[i][j][ii] + bb[j];
        if constexpr (EPI == 0) {
          ((ushort*)Cv)[idx] = f2b(v);
        } else if constexpr (EPI == 1) {
          ((ushort*)Cv)[idx] = f2b(fast_gelu(v));
        } else {
          ((float*)Cv)[idx] = v + resid[idx];
        }
      }
    }
  }
#undef STAGE_A
#undef STAGE_B
#undef PAP
#undef PBP
}

// ---------------------------------------------------------------------------
// MFMA attention.  One block (4 waves) per (b,h).
// K is now staged in LDS (XOR-swizzled, read via ds_read_b128) -- Phase 2
// previously re-loaded each K fragment from global per (wave, qt, kt) with
// 16-row-scattered 64B segments; staging eliminates the redundant L2 traffic.
// LDS 82KB -> 1 block/CU.
// ---------------------------------------------------------------------------
#define PW_STRIDE 228   // elems per row; 456B: 8B-aligned (b64 reads), ~4-way banks
__global__ __launch_bounds__(256) void attn_kernel(
    const ushort* __restrict__ qkv, const ushort* __restrict__ pos_bf,
    ushort* __restrict__ ctx) {
  int bh = blockIdx.x;
  int b = bh >> 4, h = bh & 15;
  __shared__ ushort Vt[64][PW_STRIDE];       // V^T: Vt[d][k]
  __shared__ ushort Pw[4][16][PW_STRIDE];    // per-wave: T strip, then exp(S)
  __shared__ __align__(16) ushort Klds[200 * 64];  // K rows, 16B-slot XOR swizzle
  int t = threadIdx.x, lane = t & 63, wave = t >> 6;
  int r15 = lane & 15, quad = lane >> 4;
  const size_t base = ((size_t)b * S_LEN) * 3072 + (size_t)h * 64;

  // zero Vt pad cols 200..227
  for (int i = t; i < 64 * 28; i += 256) Vt[i / 28][200 + (i % 28)] = 0;
  // stage V transposed
  for (int i = t; i < 800; i += 256) {
    int kp = i >> 3, d0 = (i & 7) * 8;
    int k = kp * 2;
    union { uint4 v; ushort u[8]; } r0, r1;
    r0.v = *(const uint4*)&qkv[base + (size_t)k * 3072 + 2048 + d0];
    r1.v = *(const uint4*)&qkv[base + (size_t)(k + 1) * 3072 + 2048 + d0];
#pragma unroll
    for (int j = 0; j < 8; ++j) {
      ushort2 w2; w2.x = r0.u[j]; w2.y = r1.u[j];
      *(ushort2*)&Vt[d0 + j][k] = w2;
    }
  }
  // stage K with 16B-slot swizzle: row k, slot s -> phys slot s^(k&7).
  // write: 8-lane groups cover all 32 banks (2 lanes/bank across wave = free);
  // read: rows r/r+8 alias to same banks = 2-way = free (m136).
  for (int i = t; i < 1600; i += 256) {
    int k = i >> 3, s = i & 7;
    uint4 v = *(const uint4*)&qkv[base + (size_t)k * 3072 + 1024 + s * 8];
    *(uint4*)&Klds[k * 64 + ((s ^ (k & 7)) << 3)] = v;
  }
  __syncthreads();

  for (int idx = wave; idx < 13; idx += 4) {
    int qt = (int)((0x3421058769ABCull >> (4 * idx)) & 0xFull);
    int q0 = qt * 16;
    int qrow = q0 + r15; if (qrow > 199) qrow = 199;
    const ushort* qp = qkv + base + (size_t)qrow * 3072;
    bf16x8 aq0 = ld_g16(qp + quad * 8);
    bf16x8 aq1 = ld_g16(qp + 32 + quad * 8);
    ushort* pw = &Pw[wave][0][0];

    // ---- Phase 1: T strip = Q @ P^T ----
#pragma unroll
    for (int dt = 0; dt < 13; ++dt) {
      if (dt > qt) continue;
      int prow = dt * 16 + r15; if (prow > 199) prow = 199;
      const ushort* pp = pos_bf + (size_t)prow * 64;
      bf16x8 p0 = ld_g16(pp + quad * 8);
      bf16x8 p1 = ld_g16(pp + 32 + quad * 8);
      f32x4 tt = {};
      tt = __builtin_amdgcn_mfma_f32_16x16x32_bf16(aq0, p0, tt, 0, 0, 0);
      tt = __builtin_amdgcn_mfma_f32_16x16x32_bf16(aq1, p1, tt, 0, 0, 0);
#pragma unroll
      for (int ii = 0; ii < 4; ++ii)
        pw[(quad * 4 + ii) * PW_STRIDE + dt * 16 + r15] = f2b(tt[ii]);
    }

    // ---- Phase 2: scores (K fragments from LDS) ----
    f32x4 sreg[13];
    float rowmax[4] = {-3.0e38f, -3.0e38f, -3.0e38f, -3.0e38f};
#pragma unroll
    for (int kt = 0; kt < 13; ++kt) {
      if (kt > qt) continue;
      int krow = kt * 16 + r15; if (krow > 199) krow = 199;
      int kb7 = krow & 7;
      bf16x8 k0 = *(const bf16x8*)&Klds[krow * 64 + ((quad ^ kb7) << 3)];
      bf16x8 k1 = *(const bf16x8*)&Klds[krow * 64 + (((quad + 4) ^ kb7) << 3)];
      f32x4 s = {};
      s = __builtin_amdgcn_mfma_f32_16x16x32_bf16(aq0, k0, s, 0, 0, 0);
      s = __builtin_amdgcn_mfma_f32_16x16x32_bf16(aq1, k1, s, 0, 0, 0);
      int k = kt * 16 + r15;
#pragma unroll
      for (int ii = 0; ii < 4; ++ii) {
        int q = q0 + quad * 4 + ii;
        float v;
        if (k <= q) {
          v = s[ii] * 0.125f + b2f(pw[(quad * 4 + ii) * PW_STRIDE + (q - k)]);
        } else {
          v = -1.0e30f;
        }
        s[ii] = v;
        rowmax[ii] = fmaxf(rowmax[ii], v);
      }
      sreg[kt] = s;
    }
#pragma unroll
    for (int off = 8; off; off >>= 1)
#pragma unroll
      for (int ii = 0; ii < 4; ++ii)
        rowmax[ii] = fmaxf(rowmax[ii], __shfl_xor(rowmax[ii], off));

    float rsum[4] = {0.f, 0.f, 0.f, 0.f};
#pragma unroll
    for (int kt = 0; kt < 13; ++kt) {
      if (kt > qt) continue;
#pragma unroll
      for (int ii = 0; ii < 4; ++ii) {
        float e = __expf(sreg[kt][ii] - rowmax[ii]);
        rsum[ii] += e;
        pw[(quad * 4 + ii) * PW_STRIDE + kt * 16 + r15] = f2b(e);
      }
    }
    if ((qt & 1) == 0) {
#pragma unroll
      for (int ii = 0; ii < 4; ++ii)
        pw[(quad * 4 + ii) * PW_STRIDE + (qt + 1) * 16 + r15] = 0;
    }
#pragma unroll
    for (int off = 8; off; off >>= 1)
#pragma unroll
      for (int ii = 0; ii < 4; ++ii)
        rsum[ii] += __shfl_xor(rsum[ii], off);
    float rinv[4];
#pragma unroll
    for (int ii = 0; ii < 4; ++ii) rinv[ii] = 1.0f / rsum[ii];

    // ---- Phase 3: ctx = exp(S) @ V ----
    int nk = (q0 + 15) / 32 + 1;
    f32x4 acc[4] = {};
#pragma unroll
    for (int k32 = 0; k32 < 7; ++k32) {
      if (k32 >= nk) continue;
      bf16x8 ap = ld_lds8x2(&pw[r15 * PW_STRIDE + k32 * 32 + quad * 8]);
#pragma unroll
      for (int n = 0; n < 4; ++n) {
        bf16x8 bv = ld_lds8x2(&Vt[n * 16 + r15][k32 * 32 + quad * 8]);
        acc[n] = __builtin_amdgcn_mfma_f32_16x16x32_bf16(ap, bv, acc[n], 0, 0, 0);
      }
    }
#pragma unroll
    for (int n = 0; n < 4; ++n)
#pragma unroll
      for (int ii = 0; ii < 4; ++ii) {
        int q = q0 + quad * 4 + ii;
        if (q < S_LEN)
          ctx[((size_t)(b * S_LEN + q)) * H_DIM + h * 64 + n * 16 + r15] =
              f2b(acc[n][ii] * rinv[ii]);
      }
  }
}

// ---------------------------------------------------------------------------
// Launcher.  Two workspace layouts:
//  UNCHUNKED (needs ~148 MB): [w1_t][w2_t][bqkv|pos_bf]
//    [slotD 26.2MB: wqkv_t+wo_t early -> h2 after wo]
//    [slotE 104.86MB: hbf@0 + qkv@26.2M early -> ctx@0 -> gbuf whole]
//  CHUNKED fallback (130 MB): FF in 2 row-chunks.
// ---------------------------------------------------------------------------
extern "C" void kernel_launch(void* const* d_in, const int* in_sizes, int n_in,
                              void* d_out, int out_size, void* d_ws, size_t ws_size,
                              hipStream_t stream) {
  (void)in_sizes; (void)n_in; (void)out_size;
  const float* x    = (const float*)d_in[0];
  const float* timev= (const float*)d_in[1];
  const float* wq   = (const float*)d_in[2];
  const float* bq   = (const float*)d_in[3];
  const float* wk   = (const float*)d_in[4];
  const float* bk   = (const float*)d_in[5];
  const float* wv   = (const float*)d_in[6];
  const float* bv   = (const float*)d_in[7];
  const float* wo   = (const float*)d_in[8];
  const float* bo   = (const float*)d_in[9];
  const float* wt   = (const float*)d_in[10];
  const float* bt   = (const float*)d_in[11];
  const float* pos  = (const float*)d_in[12];
  const float* g1   = (const float*)d_in[13];
  const float* be1  = (const float*)d_in[14];
  const float* g2   = (const float*)d_in[15];
  const float* be2  = (const float*)d_in[16];
  const float* w1   = (const float*)d_in[17];
  const float* bf1  = (const float*)d_in[18];
  const float* w2   = (const float*)d_in[19];
  const float* bf2  = (const float*)d_in[20];

  const size_t SZ_W1T  = (size_t)4096 * 1024 * 2;   // 8.39 MB
  const size_t SZ_W2T  = (size_t)1024 * 4096 * 2;   // 8.39 MB
  const size_t SZ_SM   = 65536;                     // bqkv 12KB + pos_bf 25.6KB
  const size_t SZ_D    = (size_t)NROWS * H_DIM * 2; // 26.21 MB
  const size_t SZ_E    = (size_t)NROWS * FF_DIM * 2;// 104.86 MB
  const size_t NEED_UN = SZ_W1T + SZ_W2T + SZ_SM + SZ_D + SZ_E;  // ~147.9 MB

  float* res2 = (float*)d_out;

  if (ws_size >= NEED_UN) {
    // ---------------- unchunked layout ----------------
    char* ws = (char*)d_ws;
    ushort* w1_t   = (ushort*)ws;  ws += SZ_W1T;
    ushort* w2_t   = (ushort*)ws;  ws += SZ_W2T;
    float*  bqkv   = (float*)ws;
    ushort* pos_bf = (ushort*)(ws + 16384);  ws += SZ_SM;
    char*   slotD  = ws;           ws += SZ_D;
    char*   slotE  = ws;           ws += SZ_E;
    ushort* wqkv_t = (ushort*)slotD;                              // dead after QKV
    ushort* wo_t   = (ushort*)(slotD + (size_t)3072 * 1024 * 2);  // dead after wo
    ushort* h2     = (ushort*)slotD;                              // written at LN2
    ushort* hbf    = (ushort*)slotE;                              // dead after QKV
    ushort* qkv    = (ushort*)(slotE + SZ_D);                     // dead after attn
    ushort* ctx    = (ushort*)slotE;                              // over hbf
    ushort* gbuf   = (ushort*)slotE;                              // whole slot at FF

    prep_kernel<<<15489, 256, 0, stream>>>(wq, wk, wv, wo, w1, w2, bq, bk, bv, pos,
                                           wqkv_t, wo_t, w1_t, w2_t, bqkv, pos_bf,
                                           x, g1, be1, timev, wt, bt, hbf);
    gemm256<0><<<dim3(12, 50), 512, 0, stream>>>(hbf, wqkv_t, bqkv, qkv, nullptr,
                                                 NROWS, 3072, 1024);
    attn_kernel<<<B_SZ * NHEAD, 256, 0, stream>>>(qkv, pos_bf, ctx);
    gemm256<2><<<dim3(4, 50), 512, 0, stream>>>(ctx, wo_t, bo, res2, x,
                                                NROWS, 1024, 1024);
    ln_kernel<<<NROWS / 4, 256, 0, stream>>>(res2, g2, be2, h2);
    gemm256<1><<<dim3(16, 50), 512, 0, stream>>>(h2, w1_t, bf1, gbuf, nullptr,
                                                 NROWS, 4096, 1024);
    gemm256<2><<<dim3(4, 50), 512, 0, stream>>>(gbuf, w2_t, bf2, res2, res2,
                                                NROWS, 1024, 4096);
  } else {
    // ---------------- chunked fallback ----------------
    char* ws = (char*)d_ws;
    ushort* wqkv_t = (ushort*)ws;   ws += (size_t)3072 * 1024 * 2;
    ushort* wo_t   = (ushort*)ws;   ws += (size_t)1024 * 1024 * 2;
    ushort* w1_t   = (ushort*)ws;   ws += SZ_W1T;
    ushort* w2_t   = (ushort*)ws;   ws += SZ_W2T;
    float*  bqkv   = (float*)ws;    ws += (size_t)16384;
    ushort* pos_bf = (ushort*)ws;   ws += (size_t)200 * 64 * 2;
    char* r1 = ws;                  ws += (size_t)NROWS * 3072 * 2;
    ushort* qkv  = (ushort*)r1;
    ushort* h2   = (ushort*)r1;
    ushort* gbuf = (ushort*)(r1 + (size_t)NROWS * H_DIM * 2);
    char* r2 = ws;                  ws += (size_t)NROWS * 1024 * 2;
    ushort* hbf = (ushort*)r2;
    ushort* ctx = (ushort*)r2;

    prep_kernel<<<15489, 256, 0, stream>>>(wq, wk, wv, wo, w1, w2, bq, bk, bv, pos,
                                           wqkv_t, wo_t, w1_t, w2_t, bqkv, pos_bf,
                                           x, g1, be1, timev, wt, bt, hbf);
    gemm256<0><<<dim3(12, 50), 512, 0, stream>>>(hbf, wqkv_t, bqkv, qkv, nullptr,
                                                 NROWS, 3072, 1024);
    attn_kernel<<<B_SZ * NHEAD, 256, 0, stream>>>(qkv, pos_bf, ctx);
    gemm256<2><<<dim3(4, 50), 512, 0, stream>>>(ctx, wo_t, bo, res2, x,
                                                NROWS, 1024, 1024);
    ln_kernel<<<NROWS / 4, 256, 0, stream>>>(res2, g2, be2, h2);
    for (int c = 0; c < 2; ++c) {
      size_t ro = (size_t)c * 6400;
      gemm256<1><<<dim3(16, 25), 512, 0, stream>>>(h2 + ro * 1024, w1_t, bf1, gbuf, nullptr,
                                                   6400, 4096, 1024);
      gemm_bt<2><<<dim3(8, 50), 256, 0, stream>>>(gbuf, w2_t, bf2, (float*)d_out + ro * 1024,
                                                  res2 + ro * 1024, 6400, 1024, 4096);
    }
  }
}

// Round 10
// 640.610 us; speedup vs baseline: 1.0808x; 1.0808x over previous
//
#include <hip/hip_runtime.h>

// Problem constants
#define B_SZ   64
#define S_LEN  200
#define H_DIM  1024
#define NHEAD  16
#define HDIM   64
#define FF_DIM 4096
#define NROWS  (B_SZ * S_LEN)   // 12800

typedef __bf16 bf16x8 __attribute__((ext_vector_type(8)));
typedef float  f32x4  __attribute__((ext_vector_type(4)));

#define GLOBAL_AS __attribute__((address_space(1)))
#define LDS_AS    __attribute__((address_space(3)))

__device__ __forceinline__ void g2lds16(const void* g, void* l) {
  __builtin_amdgcn_global_load_lds((const GLOBAL_AS void*)g, (LDS_AS void*)l, 16, 0, 0);
}

__device__ __forceinline__ float b2f(ushort u) {
  return __uint_as_float(((unsigned int)u) << 16);
}
__device__ __forceinline__ ushort f2b(float f) {
  unsigned int u = __float_as_uint(f);
  u += 0x7fffu + ((u >> 16) & 1u);   // RNE
  return (ushort)(u >> 16);
}
__device__ __forceinline__ bf16x8 ld_g16(const ushort* p) {   // 16B global load
  union { uint4 u; bf16x8 v; } r; r.u = *(const uint4*)p; return r.v;
}
__device__ __forceinline__ bf16x8 ld_lds8x2(const ushort* p) { // 2x ds_read_b64
  union { uint2 u[2]; bf16x8 v; } r;
  r.u[0] = *(const uint2*)p;
  r.u[1] = *(const uint2*)(p + 4);
  return r.v;
}

// ---------------------------------------------------------------------------
// Fast exact-GELU: erf via Abramowitz-Stegun 7.1.26 (|err|<=1.5e-7).
// ---------------------------------------------------------------------------
__device__ __forceinline__ float fast_gelu(float v) {
  float xe = v * 0.70710678118f;
  float ax = fabsf(xe);
  float t  = __builtin_amdgcn_rcpf(fmaf(0.3275911f, ax, 1.0f));
  float y  = fmaf(t, 1.061405429f, -1.453152027f);
  y = fmaf(t, y, 1.421413741f);
  y = fmaf(t, y, -0.284496736f);
  y = fmaf(t, y, 0.254829592f);
  y = y * t;
  float e  = __expf(-ax * ax);
  float r  = fmaf(-y, e, 1.0f);            // erf(|xe|)
  r = copysignf(r, xe);
  return 0.5f * v * (1.0f + r);
}

// ---------------------------------------------------------------------------
// LN1 row body (shared by fused-prep and standalone LN2 kernel).
// ---------------------------------------------------------------------------
template <int HAS_TIME>
__device__ __forceinline__ void ln_row(
    int r, int lane,
    const float* __restrict__ x, const float* __restrict__ g, const float* __restrict__ be,
    const float* __restrict__ tv, const float* __restrict__ wt, const float* __restrict__ bt,
    ushort* __restrict__ out) {
  const float4* xr = (const float4*)(x + (size_t)r * H_DIM);
  float4 xv[4];
  float s = 0.f, s2 = 0.f;
#pragma unroll
  for (int k = 0; k < 4; ++k) {
    xv[k] = xr[lane + 64 * k];
    s  += xv[k].x + xv[k].y + xv[k].z + xv[k].w;
    s2 += xv[k].x * xv[k].x + xv[k].y * xv[k].y + xv[k].z * xv[k].z + xv[k].w * xv[k].w;
  }
#pragma unroll
  for (int off = 32; off; off >>= 1) {
    s  += __shfl_xor(s, off);
    s2 += __shfl_xor(s2, off);
  }
  float m    = s * (1.0f / H_DIM);
  float var  = s2 * (1.0f / H_DIM) - m * m;
  float rstd = rsqrtf(var + 1e-5f);
  float tval = HAS_TIME ? tv[r] : 0.0f;
  ushort4* orow = (ushort4*)(out + (size_t)r * H_DIM);
#pragma unroll
  for (int k = 0; k < 4; ++k) {
    float4 gv = ((const float4*)g)[lane + 64 * k];
    float4 bv = ((const float4*)be)[lane + 64 * k];
    float v0 = (xv[k].x - m) * rstd * gv.x + bv.x;
    float v1 = (xv[k].y - m) * rstd * gv.y + bv.y;
    float v2 = (xv[k].z - m) * rstd * gv.z + bv.z;
    float v3 = (xv[k].w - m) * rstd * gv.w + bv.w;
    if (HAS_TIME) {
      float4 wv = ((const float4*)wt)[lane + 64 * k];
      float4 btv = ((const float4*)bt)[lane + 64 * k];
      v0 += tval * wv.x + btv.x;
      v1 += tval * wv.y + btv.y;
      v2 += tval * wv.z + btv.z;
      v3 += tval * wv.w + btv.w;
    }
    ushort4 o;
    o.x = f2b(v0); o.y = f2b(v1); o.z = f2b(v2); o.w = f2b(v3);
    orow[lane + 64 * k] = o;
  }
}

// ---------------------------------------------------------------------------
// Mega prep kernel: 6 weight transposes + bias concat + pos slice + LN1.
// Blocks 0..12287: transpose tiles.  12288: extras.  12289..15488: LN1 rows.
// ---------------------------------------------------------------------------
__global__ __launch_bounds__(256) void prep_kernel(
    const float* __restrict__ wq, const float* __restrict__ wk,
    const float* __restrict__ wv, const float* __restrict__ wo,
    const float* __restrict__ w1, const float* __restrict__ w2,
    const float* __restrict__ bq, const float* __restrict__ bk,
    const float* __restrict__ bv_, const float* __restrict__ pos,
    ushort* __restrict__ wqkv_t, ushort* __restrict__ wo_t,
    ushort* __restrict__ w1_t, ushort* __restrict__ w2_t,
    float* __restrict__ bqkv, ushort* __restrict__ pos_bf,
    const float* __restrict__ x, const float* __restrict__ g1,
    const float* __restrict__ be1, const float* __restrict__ tv,
    const float* __restrict__ wt, const float* __restrict__ bt,
    ushort* __restrict__ hbf) {
  int id = blockIdx.x;
  if (id < 12288) {
    const float* src; ushort* dst; int K, N, tile;
    if (id < 4096) {
      K = 1024; N = 1024; tile = id & 1023;
      int m = id >> 10;  // 0:wq 1:wk 2:wv 3:wo
      src = (m == 0) ? wq : (m == 1) ? wk : (m == 2) ? wv : wo;
      dst = (m == 3) ? wo_t : wqkv_t + (size_t)m * 1024 * 1024;
    } else if (id < 8192) {
      K = 1024; N = 4096; tile = id - 4096; src = w1; dst = w1_t;
    } else {
      K = 4096; N = 1024; tile = id - 8192; src = w2; dst = w2_t;
    }
    int nx = N >> 5;
    int nb = (tile % nx) * 32, kb = (tile / nx) * 32;
    __shared__ float t32[32][33];
    int tx = threadIdx.x & 31, ty = threadIdx.x >> 5;   // 32 x 8
#pragma unroll
    for (int i = 0; i < 4; ++i)
      t32[ty + i * 8][tx] = src[(size_t)(kb + ty + i * 8) * N + nb + tx];
    __syncthreads();
#pragma unroll
    for (int i = 0; i < 4; ++i)
      dst[(size_t)(nb + ty + i * 8) * K + kb + tx] = f2b(t32[tx][ty + i * 8]);
  } else if (id == 12288) {
    int t = threadIdx.x;
    for (int i = t; i < 1024; i += 256) {
      bqkv[i] = bq[i]; bqkv[1024 + i] = bk[i]; bqkv[2048 + i] = bv_[i];
    }
    for (int i = t; i < 12800; i += 256)
      pos_bf[i] = f2b(pos[(size_t)199 * 64 + i]);
  } else {
    int wave = threadIdx.x >> 6, lane = threadIdx.x & 63;
    int r = (id - 12289) * 4 + wave;
    ln_row<1>(r, lane, x, g1, be1, tv, wt, bt, hbf);
  }
}

// ---------------------------------------------------------------------------
// Standalone LN (LN2): 4 rows/block, one wave per row.
// ---------------------------------------------------------------------------
__global__ __launch_bounds__(256) void ln_kernel(
    const float* __restrict__ x, const float* __restrict__ g, const float* __restrict__ be,
    ushort* __restrict__ out) {
  int wave = threadIdx.x >> 6, lane = threadIdx.x & 63;
  int r = blockIdx.x * 4 + wave;
  ln_row<0>(r, lane, x, g, be, nullptr, nullptr, nullptr, out);
}

// ---------------------------------------------------------------------------
// 128x128 GEMM (chunked-FF2 fallback only).  Row-major XCD decode.
// ---------------------------------------------------------------------------
template <int EPI>
__global__ __launch_bounds__(256) void gemm_bt(
    const ushort* __restrict__ A, const ushort* __restrict__ Bt,
    const float* __restrict__ bias, void* __restrict__ Cv,
    const float* __restrict__ resid, int M, int N, int K) {
  __shared__ __align__(16) ushort As[2 * 128 * 32];   // [kh][row][32]
  __shared__ __align__(16) ushort Bs[2 * 128 * 32];
  int t = threadIdx.x;
  int lane = t & 63, wave = t >> 6;
  int wm = wave >> 1, wn = wave & 1;
  int r15 = lane & 15, quad = lane >> 4;
  int nwg = gridDim.x * gridDim.y;
  int bid = blockIdx.y * gridDim.x + blockIdx.x;
  int swz = (bid & 7) * (nwg >> 3) + (bid >> 3);
  int bx = swz % gridDim.x, by = swz / gridDim.x;
  size_t row0 = (size_t)by * 128;
  size_t col0 = (size_t)bx * 128;

  int srow = (lane >> 2), scol = (lane & 3) * 8;
  const ushort* ga0 = A  + (row0 + wave * 32 +      srow) * K + scol;
  const ushort* ga1 = A  + (row0 + wave * 32 + 16 + srow) * K + scol;
  const ushort* gb0 = Bt + (col0 + wave * 32 +      srow) * K + scol;
  const ushort* gb1 = Bt + (col0 + wave * 32 + 16 + srow) * K + scol;
  ushort* la0 = As + (wave * 32) * 32;
  ushort* la1 = As + (wave * 32 + 16) * 32;
  ushort* lb0 = Bs + (wave * 32) * 32;
  ushort* lb1 = Bs + (wave * 32 + 16) * 32;

  f32x4 acc[4][4] = {};

  for (int k0 = 0; k0 < K; k0 += 64) {
#pragma unroll
    for (int kh = 0; kh < 2; ++kh) {
      int go = k0 + kh * 32, lo = kh * 4096;
      g2lds16(ga0 + go, la0 + lo);
      g2lds16(ga1 + go, la1 + lo);
      g2lds16(gb0 + go, lb0 + lo);
      g2lds16(gb1 + go, lb1 + lo);
    }
    __syncthreads();
#pragma unroll
    for (int kh = 0; kh < 2; ++kh) {
      bf16x8 af[4], bfr[4];
#pragma unroll
      for (int i = 0; i < 4; ++i)
        af[i] = *(const bf16x8*)&As[kh * 4096 + (wm * 64 + i * 16 + r15) * 32 + quad * 8];
#pragma unroll
      for (int j = 0; j < 4; ++j)
        bfr[j] = *(const bf16x8*)&Bs[kh * 4096 + (wn * 64 + j * 16 + r15) * 32 + quad * 8];
#pragma unroll
      for (int i = 0; i < 4; ++i)
#pragma unroll
        for (int j = 0; j < 4; ++j)
          acc[i][j] = __builtin_amdgcn_mfma_f32_16x16x32_bf16(af[i], bfr[j], acc[i][j], 0, 0, 0);
    }
    __syncthreads();
  }

  int mbase = (int)row0 + wm * 64;
  int nbase = (int)col0 + wn * 64;
  float bb[4];
#pragma unroll
  for (int j = 0; j < 4; ++j) bb[j] = bias[nbase + j * 16 + r15];
#pragma unroll
  for (int i = 0; i < 4; ++i) {
#pragma unroll
    for (int ii = 0; ii < 4; ++ii) {
      int row = mbase + i * 16 + quad * 4 + ii;
      size_t rb = (size_t)row * N + nbase + r15;
#pragma unroll
      for (int j = 0; j < 4; ++j) {   // j innermost: 4 stores share a 128B line
        size_t idx = rb + j * 16;
        float v = acc[i][j][ii] + bb[j];
        if constexpr (EPI == 0) {
          ((ushort*)Cv)[idx] = f2b(v);
        } else if constexpr (EPI == 1) {
          ((ushort*)Cv)[idx] = f2b(fast_gelu(v));
        } else {
          ((float*)Cv)[idx] = v + resid[idx];
        }
      }
    }
  }
}

// ---------------------------------------------------------------------------
// 256x256 8-phase GEMM (round-4 schedule, best measured).
// Row-major XCD decode; write-combined epilogue.
// ---------------------------------------------------------------------------
template <int IB>
__device__ __forceinline__ void mfma_blk(f32x4 (&acc)[8][4],
                                         const bf16x8 (&af)[4], const bf16x8 (&bfr)[4]) {
#pragma unroll
  for (int i = 0; i < 4; ++i)
#pragma unroll
    for (int j = 0; j < 4; ++j)
      acc[IB + i][j] =
          __builtin_amdgcn_mfma_f32_16x16x32_bf16(af[i], bfr[j], acc[IB + i][j], 0, 0, 0);
}

__device__ __forceinline__ bf16x8 rdfrag(const ushort* plane, int r, int quad) {
  // logical (row r, 16B-slot quad) -> physical slot quad ^ ((r>>1)&3)
  return *(const bf16x8*)(plane + r * 32 + ((quad ^ ((r >> 1) & 3)) << 3));
}

__device__ __forceinline__ void read_q0(bf16x8 (&af)[4], bf16x8 (&bfr)[4],
                                        const ushort* pA, const ushort* pB,
                                        int wn1, int r15, int quad) {
#pragma unroll
  for (int j = 0; j < 4; ++j) bfr[j] = rdfrag(pB, wn1 * 64 + j * 16 + r15, quad);
#pragma unroll
  for (int i = 0; i < 4; ++i) af[i] = rdfrag(pA, i * 16 + r15, quad);
}
__device__ __forceinline__ void read_q1(bf16x8 (&af)[4], const ushort* pA,
                                        int r15, int quad) {
#pragma unroll
  for (int i = 0; i < 4; ++i) af[i] = rdfrag(pA, 64 + i * 16 + r15, quad);
}

#define VMW8() asm volatile("s_waitcnt vmcnt(8)" ::: "memory")
#define VMW4() asm volatile("s_waitcnt vmcnt(4)" ::: "memory")
#define VMW0() asm volatile("s_waitcnt vmcnt(0)" ::: "memory")
#define BARX() __builtin_amdgcn_s_barrier()
#define PRIO1() __builtin_amdgcn_s_setprio(1)
#define PRIO0() __builtin_amdgcn_s_setprio(0)

template <int EPI>
__global__ __launch_bounds__(512) void gemm256(
    const ushort* __restrict__ A, const ushort* __restrict__ Bt,
    const float* __restrict__ bias, void* __restrict__ Cv,
    const float* __restrict__ resid, int M, int N, int K) {
  __shared__ __align__(16) ushort lds[2][2][2][2][4096];  // [buf][A/B][half][kh][128*32]
  const int t = threadIdx.x;
  const int lane = t & 63, wave = t >> 6;
  const int wm = wave >> 2;            // A half this wave consumes
  const int wn = wave & 3;
  const int wn1 = wn & 1;
  const int bh = wn >> 1;              // B half this wave consumes
  const int r15 = lane & 15, quad = lane >> 4;
  // XCD swizzle (T1), row-major decode: consecutive swz share by (A-panel)
  int nwg = gridDim.x * gridDim.y;
  int bid = blockIdx.y * gridDim.x + blockIdx.x;
  int swz = (bid & 7) * (nwg >> 3) + (bid >> 3);
  int bx = swz % gridDim.x, by = swz / gridDim.x;
  const size_t row0 = (size_t)by * 256;
  const size_t col0 = (size_t)bx * 256;

  const int gwA = wave & 3;
  const int gwB = ((wave >> 1) & 2) | (wave & 1);

  const ushort *gA0, *gA1, *gB0, *gB1;
  {
    int p0 = gwA * 128 + lane;
    int p1 = p0 + 64;
    int ra0 = p0 >> 2, sa0 = (p0 & 3) ^ ((p0 >> 3) & 3);
    int ra1 = p1 >> 2, sa1 = (p1 & 3) ^ ((p1 >> 3) & 3);
    gA0 = A + (row0 + wm * 128 + ra0) * K + sa0 * 8;
    gA1 = A + (row0 + wm * 128 + ra1) * K + sa1 * 8;
    int q0 = gwB * 128 + lane;
    int q1 = q0 + 64;
    int rb0 = q0 >> 2, sb0 = (q0 & 3) ^ ((q0 >> 3) & 3);
    int rb1 = q1 >> 2, sb1 = (q1 & 3) ^ ((q1 >> 3) & 3);
    gB0 = Bt + (col0 + bh * 128 + rb0) * K + sb0 * 8;
    gB1 = Bt + (col0 + bh * 128 + rb1) * K + sb1 * 8;
  }
  const int ldsA0 = gwA * 1024, ldsA1 = gwA * 1024 + 512;   // ushort offsets
  const int ldsB0 = gwB * 1024, ldsB1 = gwB * 1024 + 512;

#define STAGE_A(nb_, skh_, kof_)                                        \
  do {                                                                  \
    g2lds16(gA0 + (kof_) + (skh_) * 32, &lds[nb_][0][wm][skh_][ldsA0]); \
    g2lds16(gA1 + (kof_) + (skh_) * 32, &lds[nb_][0][wm][skh_][ldsA1]); \
  } while (0)
#define STAGE_B(nb_, skh_, kof_)                                        \
  do {                                                                  \
    g2lds16(gB0 + (kof_) + (skh_) * 32, &lds[nb_][1][bh][skh_][ldsB0]); \
    g2lds16(gB1 + (kof_) + (skh_) * 32, &lds[nb_][1][bh][skh_][ldsB1]); \
  } while (0)
#define PAP(b_, k_) (&lds[b_][0][wm][k_][0])
#define PBP(b_, k_) (&lds[b_][1][bh][k_][0])

  f32x4 acc[8][4] = {};

  // prologue: tile0 full + tile1 kh0 (6 stage ops = 12 loads/thread)
  STAGE_A(0, 0, 0);
  STAGE_B(0, 0, 0);
  STAGE_A(0, 1, 0);
  STAGE_B(0, 1, 0);
  STAGE_A(1, 0, 64);
  STAGE_B(1, 0, 64);
  VMW8();                       // tile0 kh0 (A,B) resident; 8 loads in flight
  BARX();

#define ITER_BODY(LAST_, ka_)                                                  \
  {                                                                            \
    bf16x8 af[4], bfr[4];                                                      \
    /* P0: buf0 kh0 Q0 */                                                      \
    read_q0(af, bfr, PAP(0, 0), PBP(0, 0), wn1, r15, quad);                    \
    STAGE_A(1, 1, (ka_) + 64);                                                 \
    BARX(); PRIO1(); mfma_blk<0>(acc, af, bfr); PRIO0(); BARX();               \
    /* P1: buf0 kh0 Q1 */                                                      \
    read_q1(af, PAP(0, 0), r15, quad);                                         \
    STAGE_B(1, 1, (ka_) + 64);                                                 \
    BARX(); PRIO1(); mfma_blk<4>(acc, af, bfr); PRIO0();                       \
    VMW8(); BARX();                                                            \
    /* P2: buf0 kh1 Q0 */                                                      \
    read_q0(af, bfr, PAP(0, 1), PBP(0, 1), wn1, r15, quad);                    \
    if (!(LAST_)) STAGE_A(0, 0, (ka_) + 128);                                  \
    BARX(); PRIO1(); mfma_blk<0>(acc, af, bfr); PRIO0(); BARX();               \
    /* P3: buf0 kh1 Q1 */                                                      \
    read_q1(af, PAP(0, 1), r15, quad);                                         \
    if (!(LAST_)) STAGE_B(0, 0, (ka_) + 128);                                  \
    BARX(); PRIO1(); mfma_blk<4>(acc, af, bfr); PRIO0();                       \
    if (LAST_) { VMW4(); } else { VMW8(); }                                    \
    BARX();                                                                    \
    /* P4: buf1 kh0 Q0 */                                                      \
    read_q0(af, bfr, PAP(1, 0), PBP(1, 0), wn1, r15, quad);                    \
    if (!(LAST_)) STAGE_A(0, 1, (ka_) + 128);                                  \
    BARX(); PRIO1(); mfma_blk<0>(acc, af, bfr); PRIO0(); BARX();               \
    /* P5: buf1 kh0 Q1 */                                                      \
    read_q1(af, PAP(1, 0), r15, quad);                                         \
    if (!(LAST_)) STAGE_B(0, 1, (ka_) + 128);                                  \
    BARX(); PRIO1(); mfma_blk<4>(acc, af, bfr); PRIO0();                       \
    if (LAST_) { VMW0(); } else { VMW8(); }                                    \
    BARX();                                                                    \
    /* P6: buf1 kh1 Q0 */                                                      \
    read_q0(af, bfr, PAP(1, 1), PBP(1, 1), wn1, r15, quad);                    \
    if (!(LAST_)) STAGE_A(1, 0, (ka_) + 192);                                  \
    BARX(); PRIO1(); mfma_blk<0>(acc, af, bfr); PRIO0(); BARX();               \
    /* P7: buf1 kh1 Q1 */                                                      \
    read_q1(af, PAP(1, 1), r15, quad);                                         \
    if (!(LAST_)) STAGE_B(1, 0, (ka_) + 192);                                  \
    BARX(); PRIO1(); mfma_blk<4>(acc, af, bfr); PRIO0();                       \
    if (!(LAST_)) { VMW8(); }                                                  \
    BARX();                                                                    \
  }

  const int NI = K >> 7;   // two 64-wide K-tiles per iteration
  for (int it = 0; it < NI - 1; ++it) {
    ITER_BODY(0, it << 7);
  }
  ITER_BODY(1, (NI - 1) << 7);
#undef ITER_BODY

  // epilogue (write-combined: j innermost so 4 stores share a 128B line)
  int mbase = (int)row0 + wm * 128;
  int nbase = (int)col0 + wn * 64;
  float bb[4];
#pragma unroll
  for (int j = 0; j < 4; ++j) bb[j] = bias[nbase + j * 16 + r15];
#pragma unroll
  for (int i = 0; i < 8; ++i) {
#pragma unroll
    for (int ii = 0; ii < 4; ++ii) {
      int row = mbase + i * 16 + quad * 4 + ii;
      size_t rb = (size_t)row * N + nbase + r15;
#pragma unroll
      for (int j = 0; j < 4; ++j) {
        size_t idx = rb + j * 16;
        float v = acc[i][j][ii] + bb[j];
        if constexpr (EPI == 0) {
          ((ushort*)Cv)[idx] = f2b(v);
        } else if constexpr (EPI == 1) {
          ((ushort*)Cv)[idx] = f2b(fast_gelu(v));
        } else {
          ((float*)Cv)[idx] = v + resid[idx];
        }
      }
    }
  }
#undef STAGE_A
#undef STAGE_B
#undef PAP
#undef PBP
}

// ---------------------------------------------------------------------------
// MFMA attention.  One block (4 waves) per (b,h).  58KB LDS -> 2 blocks/CU
// (round-8 K-staging pushed LDS to 84KB -> 1 block/CU and regressed +47us;
//  K re-reads are L2-hits hidden by TLP -- do NOT stage K).
// ---------------------------------------------------------------------------
#define PW_STRIDE 228   // elems per row; 456B: 8B-aligned (b64 reads), ~4-way banks
__global__ __launch_bounds__(256) void attn_kernel(
    const ushort* __restrict__ qkv, const ushort* __restrict__ pos_bf,
    ushort* __restrict__ ctx) {
  int bh = blockIdx.x;
  int b = bh >> 4, h = bh & 15;
  __shared__ ushort Vt[64][PW_STRIDE];       // V^T: Vt[d][k]
  __shared__ ushort Pw[4][16][PW_STRIDE];    // per-wave: T strip, then exp(S)
  int t = threadIdx.x, lane = t & 63, wave = t >> 6;
  int r15 = lane & 15, quad = lane >> 4;
  const size_t base = ((size_t)b * S_LEN) * 3072 + (size_t)h * 64;

  // zero Vt pad cols 200..227
  for (int i = t; i < 64 * 28; i += 256) Vt[i / 28][200 + (i % 28)] = 0;
  // stage V transposed
  for (int i = t; i < 800; i += 256) {
    int kp = i >> 3, d0 = (i & 7) * 8;
    int k = kp * 2;
    union { uint4 v; ushort u[8]; } r0, r1;
    r0.v = *(const uint4*)&qkv[base + (size_t)k * 3072 + 2048 + d0];
    r1.v = *(const uint4*)&qkv[base + (size_t)(k + 1) * 3072 + 2048 + d0];
#pragma unroll
    for (int j = 0; j < 8; ++j) {
      ushort2 w2; w2.x = r0.u[j]; w2.y = r1.u[j];
      *(ushort2*)&Vt[d0 + j][k] = w2;
    }
  }
  __syncthreads();

  for (int idx = wave; idx < 13; idx += 4) {
    int qt = (int)((0x3421058769ABCull >> (4 * idx)) & 0xFull);
    int q0 = qt * 16;
    int qrow = q0 + r15; if (qrow > 199) qrow = 199;
    const ushort* qp = qkv + base + (size_t)qrow * 3072;
    bf16x8 aq0 = ld_g16(qp + quad * 8);
    bf16x8 aq1 = ld_g16(qp + 32 + quad * 8);
    ushort* pw = &Pw[wave][0][0];

    // ---- Phase 1: T strip = Q @ P^T ----
#pragma unroll
    for (int dt = 0; dt < 13; ++dt) {
      if (dt > qt) continue;
      int prow = dt * 16 + r15; if (prow > 199) prow = 199;
      const ushort* pp = pos_bf + (size_t)prow * 64;
      bf16x8 p0 = ld_g16(pp + quad * 8);
      bf16x8 p1 = ld_g16(pp + 32 + quad * 8);
      f32x4 tt = {};
      tt = __builtin_amdgcn_mfma_f32_16x16x32_bf16(aq0, p0, tt, 0, 0, 0);
      tt = __builtin_amdgcn_mfma_f32_16x16x32_bf16(aq1, p1, tt, 0, 0, 0);
#pragma unroll
      for (int ii = 0; ii < 4; ++ii)
        pw[(quad * 4 + ii) * PW_STRIDE + dt * 16 + r15] = f2b(tt[ii]);
    }

    // ---- Phase 2: scores ----
    f32x4 sreg[13];
    float rowmax[4] = {-3.0e38f, -3.0e38f, -3.0e38f, -3.0e38f};
#pragma unroll
    for (int kt = 0; kt < 13; ++kt) {
      if (kt > qt) continue;
      int krow = kt * 16 + r15; if (krow > 199) krow = 199;
      const ushort* kp = qkv + base + (size_t)krow * 3072 + 1024;
      bf16x8 k0 = ld_g16(kp + quad * 8);
      bf16x8 k1 = ld_g16(kp + 32 + quad * 8);
      f32x4 s = {};
      s = __builtin_amdgcn_mfma_f32_16x16x32_bf16(aq0, k0, s, 0, 0, 0);
      s = __builtin_amdgcn_mfma_f32_16x16x32_bf16(aq1, k1, s, 0, 0, 0);
      int k = kt * 16 + r15;
#pragma unroll
      for (int ii = 0; ii < 4; ++ii) {
        int q = q0 + quad * 4 + ii;
        float v;
        if (k <= q) {
          v = s[ii] * 0.125f + b2f(pw[(quad * 4 + ii) * PW_STRIDE + (q - k)]);
        } else {
          v = -1.0e30f;
        }
        s[ii] = v;
        rowmax[ii] = fmaxf(rowmax[ii], v);
      }
      sreg[kt] = s;
    }
#pragma unroll
    for (int off = 8; off; off >>= 1)
#pragma unroll
      for (int ii = 0; ii < 4; ++ii)
        rowmax[ii] = fmaxf(rowmax[ii], __shfl_xor(rowmax[ii], off));

    float rsum[4] = {0.f, 0.f, 0.f, 0.f};
#pragma unroll
    for (int kt = 0; kt < 13; ++kt) {
      if (kt > qt) continue;
#pragma unroll
      for (int ii = 0; ii < 4; ++ii) {
        float e = __expf(sreg[kt][ii] - rowmax[ii]);
        rsum[ii] += e;
        pw[(quad * 4 + ii) * PW_STRIDE + kt * 16 + r15] = f2b(e);
      }
    }
    if ((qt & 1) == 0) {
#pragma unroll
      for (int ii = 0; ii < 4; ++ii)
        pw[(quad * 4 + ii) * PW_STRIDE + (qt + 1) * 16 + r15] = 0;
    }
#pragma unroll
    for (int off = 8; off; off >>= 1)
#pragma unroll
      for (int ii = 0; ii < 4; ++ii)
        rsum[ii] += __shfl_xor(rsum[ii], off);
    float rinv[4];
#pragma unroll
    for (int ii = 0; ii < 4; ++ii) rinv[ii] = 1.0f / rsum[ii];

    // ---- Phase 3: ctx = exp(S) @ V ----
    int nk = (q0 + 15) / 32 + 1;
    f32x4 acc[4] = {};
#pragma unroll
    for (int k32 = 0; k32 < 7; ++k32) {
      if (k32 >= nk) continue;
      bf16x8 ap = ld_lds8x2(&pw[r15 * PW_STRIDE + k32 * 32 + quad * 8]);
#pragma unroll
      for (int n = 0; n < 4; ++n) {
        bf16x8 bv = ld_lds8x2(&Vt[n * 16 + r15][k32 * 32 + quad * 8]);
        acc[n] = __builtin_amdgcn_mfma_f32_16x16x32_bf16(ap, bv, acc[n], 0, 0, 0);
      }
    }
#pragma unroll
    for (int n = 0; n < 4; ++n)
#pragma unroll
      for (int ii = 0; ii < 4; ++ii) {
        int q = q0 + quad * 4 + ii;
        if (q < S_LEN)
          ctx[((size_t)(b * S_LEN + q)) * H_DIM + h * 64 + n * 16 + r15] =
              f2b(acc[n][ii] * rinv[ii]);
      }
  }
}

// ---------------------------------------------------------------------------
// Launcher.  Two workspace layouts:
//  UNCHUNKED (needs ~148 MB): [w1_t][w2_t][bqkv|pos_bf]
//    [slotD 26.2MB: wqkv_t+wo_t early -> h2 after wo]
//    [slotE 104.86MB: hbf@0 + qkv@26.2M early -> ctx@0 -> gbuf whole]
//  CHUNKED fallback (130 MB): FF in 2 row-chunks.
// ---------------------------------------------------------------------------
extern "C" void kernel_launch(void* const* d_in, const int* in_sizes, int n_in,
                              void* d_out, int out_size, void* d_ws, size_t ws_size,
                              hipStream_t stream) {
  (void)in_sizes; (void)n_in; (void)out_size;
  const float* x    = (const float*)d_in[0];
  const float* timev= (const float*)d_in[1];
  const float* wq   = (const float*)d_in[2];
  const float* bq   = (const float*)d_in[3];
  const float* wk   = (const float*)d_in[4];
  const float* bk   = (const float*)d_in[5];
  const float* wv   = (const float*)d_in[6];
  const float* bv   = (const float*)d_in[7];
  const float* wo   = (const float*)d_in[8];
  const float* bo   = (const float*)d_in[9];
  const float* wt   = (const float*)d_in[10];
  const float* bt   = (const float*)d_in[11];
  const float* pos  = (const float*)d_in[12];
  const float* g1   = (const float*)d_in[13];
  const float* be1  = (const float*)d_in[14];
  const float* g2   = (const float*)d_in[15];
  const float* be2  = (const float*)d_in[16];
  const float* w1   = (const float*)d_in[17];
  const float* bf1  = (const float*)d_in[18];
  const float* w2   = (const float*)d_in[19];
  const float* bf2  = (const float*)d_in[20];

  const size_t SZ_W1T  = (size_t)4096 * 1024 * 2;   // 8.39 MB
  const size_t SZ_W2T  = (size_t)1024 * 4096 * 2;   // 8.39 MB
  const size_t SZ_SM   = 65536;                     // bqkv 12KB + pos_bf 25.6KB
  const size_t SZ_D    = (size_t)NROWS * H_DIM * 2; // 26.21 MB
  const size_t SZ_E    = (size_t)NROWS * FF_DIM * 2;// 104.86 MB
  const size_t NEED_UN = SZ_W1T + SZ_W2T + SZ_SM + SZ_D + SZ_E;  // ~147.9 MB

  float* res2 = (float*)d_out;

  if (ws_size >= NEED_UN) {
    // ---------------- unchunked layout ----------------
    char* ws = (char*)d_ws;
    ushort* w1_t   = (ushort*)ws;  ws += SZ_W1T;
    ushort* w2_t   = (ushort*)ws;  ws += SZ_W2T;
    float*  bqkv   = (float*)ws;
    ushort* pos_bf = (ushort*)(ws + 16384);  ws += SZ_SM;
    char*   slotD  = ws;           ws += SZ_D;
    char*   slotE  = ws;           ws += SZ_E;
    ushort* wqkv_t = (ushort*)slotD;                              // dead after QKV
    ushort* wo_t   = (ushort*)(slotD + (size_t)3072 * 1024 * 2);  // dead after wo
    ushort* h2     = (ushort*)slotD;                              // written at LN2
    ushort* hbf    = (ushort*)slotE;                              // dead after QKV
    ushort* qkv    = (ushort*)(slotE + SZ_D);                     // dead after attn
    ushort* ctx    = (ushort*)slotE;                              // over hbf
    ushort* gbuf   = (ushort*)slotE;                              // whole slot at FF

    prep_kernel<<<15489, 256, 0, stream>>>(wq, wk, wv, wo, w1, w2, bq, bk, bv, pos,
                                           wqkv_t, wo_t, w1_t, w2_t, bqkv, pos_bf,
                                           x, g1, be1, timev, wt, bt, hbf);
    gemm256<0><<<dim3(12, 50), 512, 0, stream>>>(hbf, wqkv_t, bqkv, qkv, nullptr,
                                                 NROWS, 3072, 1024);
    attn_kernel<<<B_SZ * NHEAD, 256, 0, stream>>>(qkv, pos_bf, ctx);
    gemm256<2><<<dim3(4, 50), 512, 0, stream>>>(ctx, wo_t, bo, res2, x,
                                                NROWS, 1024, 1024);
    ln_kernel<<<NROWS / 4, 256, 0, stream>>>(res2, g2, be2, h2);
    gemm256<1><<<dim3(16, 50), 512, 0, stream>>>(h2, w1_t, bf1, gbuf, nullptr,
                                                 NROWS, 4096, 1024);
    gemm256<2><<<dim3(4, 50), 512, 0, stream>>>(gbuf, w2_t, bf2, res2, res2,
                                                NROWS, 1024, 4096);
  } else {
    // ---------------- chunked fallback ----------------
    char* ws = (char*)d_ws;
    ushort* wqkv_t = (ushort*)ws;   ws += (size_t)3072 * 1024 * 2;
    ushort* wo_t   = (ushort*)ws;   ws += (size_t)1024 * 1024 * 2;
    ushort* w1_t   = (ushort*)ws;   ws += SZ_W1T;
    ushort* w2_t   = (ushort*)ws;   ws += SZ_W2T;
    float*  bqkv   = (float*)ws;    ws += (size_t)16384;
    ushort* pos_bf = (ushort*)ws;   ws += (size_t)200 * 64 * 2;
    char* r1 = ws;                  ws += (size_t)NROWS * 3072 * 2;
    ushort* qkv  = (ushort*)r1;
    ushort* h2   = (ushort*)r1;
    ushort* gbuf = (ushort*)(r1 + (size_t)NROWS * H_DIM * 2);
    char* r2 = ws;                  ws += (size_t)NROWS * 1024 * 2;
    ushort* hbf = (ushort*)r2;
    ushort* ctx = (ushort*)r2;

    prep_kernel<<<15489, 256, 0, stream>>>(wq, wk, wv, wo, w1, w2, bq, bk, bv, pos,
                                           wqkv_t, wo_t, w1_t, w2_t, bqkv, pos_bf,
                                           x, g1, be1, timev, wt, bt, hbf);
    gemm256<0><<<dim3(12, 50), 512, 0, stream>>>(hbf, wqkv_t, bqkv, qkv, nullptr,
                                                 NROWS, 3072, 1024);
    attn_kernel<<<B_SZ * NHEAD, 256, 0, stream>>>(qkv, pos_bf, ctx);
    gemm256<2><<<dim3(4, 50), 512, 0, stream>>>(ctx, wo_t, bo, res2, x,
                                                NROWS, 1024, 1024);
    ln_kernel<<<NROWS / 4, 256, 0, stream>>>(res2, g2, be2, h2);
    for (int c = 0; c < 2; ++c) {
      size_t ro = (size_t)c * 6400;
      gemm256<1><<<dim3(16, 25), 512, 0, stream>>>(h2 + ro * 1024, w1_t, bf1, gbuf, nullptr,
                                                   6400, 4096, 1024);
      gemm_bt<2><<<dim3(8, 50), 256, 0, stream>>>(gbuf, w2_t, bf2, (float*)d_out + ro * 1024,
                                                  res2 + ro * 1024, 6400, 1024, 4096);
    }
  }
}